// Round 1
// baseline (444.013 us; speedup 1.0000x reference)
//
#include <hip/hip_runtime.h>
#include <hip/hip_bf16.h>

#define BATCH 4
#define SEQ   2048
#define EMB   1024
#define NH    16
#define HD    64

typedef __attribute__((ext_vector_type(8))) short short8;   // 8 bf16 (4 VGPRs) MFMA frag
typedef __attribute__((ext_vector_type(4))) float f32x4;    // MFMA accumulator

// ---------------------------------------------------------------------------
// Kernel 1: fused QKV projection.
//   C[bt, (m,h,d)] = sum_e x[bt,e] * W_m[h,e,d]     (fp32 in, bf16 out)
// Tile: 64 rows (B*T) x 64 cols (one (m,h) pair covers exactly d=0..63).
// 4 waves, each computes 16 rows x 64 cols via 16x16x32 bf16 MFMA, BK=64.
// Q output is pre-scaled by 1/sqrt(D)=0.125 (exact, applied in fp32).
// Output layout: qkv[m][b][h][t][d], bf16.
// ---------------------------------------------------------------------------
__global__ __launch_bounds__(256)
void qkv_proj_kernel(const float* __restrict__ x,
                     const float* __restrict__ Wq,
                     const float* __restrict__ Wk,
                     const float* __restrict__ Wv,
                     __hip_bfloat16* __restrict__ qkv)
{
    const int rowTile = blockIdx.x;          // 0..127 over (B*T)/64
    const int nt      = blockIdx.y;          // 0..47 = m*16 + h
    const int m       = nt >> 4;
    const int h       = nt & 15;
    const float* W  = (m == 0) ? Wq : (m == 1) ? Wk : Wv;
    const float* Wh = W + (size_t)h * (EMB * HD);   // [E][64] row-major
    const int row0  = rowTile * 64;

    // +8 bf16 pad: row stride 144B (16B-aligned, conflict-light)
    __shared__ __hip_bfloat16 As[64][72];   // x tile   [row][k]
    __shared__ __hip_bfloat16 Bs[64][72];   // W tile transposed: [d][k]

    const int tid  = threadIdx.x;
    const int wave = tid >> 6;
    const int lane = tid & 63;
    const int lr   = lane & 15;              // frag row (A) / col (B)
    const int lg   = lane >> 4;              // k-group 0..3

    f32x4 acc[4] = {};                       // 4 col-tiles of 16; rows wave*16..+15

    for (int k0 = 0; k0 < EMB; k0 += 64) {
        __syncthreads();
        {   // stage A: 64x64 fp32 -> bf16, coalesced reads, vector LDS writes
            const int r  = tid >> 2;
            const int c0 = (tid & 3) * 16;
            const float* src = x + (size_t)(row0 + r) * EMB + (k0 + c0);
            float4 f0 = ((const float4*)src)[0];
            float4 f1 = ((const float4*)src)[1];
            float4 f2 = ((const float4*)src)[2];
            float4 f3 = ((const float4*)src)[3];
            __hip_bfloat16* dst = &As[r][c0];
            dst[0]  = __float2bfloat16(f0.x); dst[1]  = __float2bfloat16(f0.y);
            dst[2]  = __float2bfloat16(f0.z); dst[3]  = __float2bfloat16(f0.w);
            dst[4]  = __float2bfloat16(f1.x); dst[5]  = __float2bfloat16(f1.y);
            dst[6]  = __float2bfloat16(f1.z); dst[7]  = __float2bfloat16(f1.w);
            dst[8]  = __float2bfloat16(f2.x); dst[9]  = __float2bfloat16(f2.y);
            dst[10] = __float2bfloat16(f2.z); dst[11] = __float2bfloat16(f2.w);
            dst[12] = __float2bfloat16(f3.x); dst[13] = __float2bfloat16(f3.y);
            dst[14] = __float2bfloat16(f3.z); dst[15] = __float2bfloat16(f3.w);
        }
        {   // stage B transposed: W[e][d] -> Bs[d][e] (coalesced reads, scalar scatter)
            const int e  = tid >> 2;
            const int d0 = (tid & 3) * 16;
            const float* src = Wh + (size_t)(k0 + e) * HD + d0;
            float4 f0 = ((const float4*)src)[0];
            float4 f1 = ((const float4*)src)[1];
            float4 f2 = ((const float4*)src)[2];
            float4 f3 = ((const float4*)src)[3];
            Bs[d0 +  0][e] = __float2bfloat16(f0.x); Bs[d0 +  1][e] = __float2bfloat16(f0.y);
            Bs[d0 +  2][e] = __float2bfloat16(f0.z); Bs[d0 +  3][e] = __float2bfloat16(f0.w);
            Bs[d0 +  4][e] = __float2bfloat16(f1.x); Bs[d0 +  5][e] = __float2bfloat16(f1.y);
            Bs[d0 +  6][e] = __float2bfloat16(f1.z); Bs[d0 +  7][e] = __float2bfloat16(f1.w);
            Bs[d0 +  8][e] = __float2bfloat16(f2.x); Bs[d0 +  9][e] = __float2bfloat16(f2.y);
            Bs[d0 + 10][e] = __float2bfloat16(f2.z); Bs[d0 + 11][e] = __float2bfloat16(f2.w);
            Bs[d0 + 12][e] = __float2bfloat16(f3.x); Bs[d0 + 13][e] = __float2bfloat16(f3.y);
            Bs[d0 + 14][e] = __float2bfloat16(f3.z); Bs[d0 + 15][e] = __float2bfloat16(f3.w);
        }
        __syncthreads();
        #pragma unroll
        for (int half = 0; half < 2; ++half) {
            short8 a = *(const short8*)&As[wave * 16 + lr][half * 32 + lg * 8];
            #pragma unroll
            for (int ct = 0; ct < 4; ++ct) {
                short8 bf = *(const short8*)&Bs[ct * 16 + lr][half * 32 + lg * 8];
                acc[ct] = __builtin_amdgcn_mfma_f32_16x16x32_bf16(a, bf, acc[ct], 0, 0, 0);
            }
        }
    }

    // epilogue: C/D layout col=lane&15, row=(lane>>4)*4+i  [measured m89/m91]
    const int b    = row0 / SEQ;
    const int tloc = (row0 % SEQ) + wave * 16;
    const float scale = (m == 0) ? 0.125f : 1.0f;   // fold 1/sqrt(D) into Q
    __hip_bfloat16* outp = qkv + (((size_t)m * BATCH + b) * NH + h) * ((size_t)SEQ * HD);
    #pragma unroll
    for (int ct = 0; ct < 4; ++ct) {
        #pragma unroll
        for (int i = 0; i < 4; ++i) {
            const int trow = tloc + lg * 4 + i;
            outp[(size_t)trow * HD + ct * 16 + lr] = __float2bfloat16(acc[ct][i] * scale);
        }
    }
}

// ---------------------------------------------------------------------------
// Kernel 2: causal flash attention.
// Block = one (b,h) and a 64-row Q tile; 4 waves x 16 q-rows each.
// KV tiles of 64. QK^T and PV via 16x16x32 bf16 MFMA; P goes through LDS.
// ---------------------------------------------------------------------------
__global__ __launch_bounds__(256)
void attn_kernel(const __hip_bfloat16* __restrict__ qkv, float* __restrict__ out)
{
    const int qt = blockIdx.x;               // q tile index
    const int h  = blockIdx.y;
    const int b  = blockIdx.z;
    const int qbase = qt * 64;

    const size_t hs = (size_t)SEQ * HD;
    const __hip_bfloat16* qp = qkv + (((size_t)0 * BATCH + b) * NH + h) * hs;
    const __hip_bfloat16* kp = qkv + (((size_t)1 * BATCH + b) * NH + h) * hs;
    const __hip_bfloat16* vp = qkv + (((size_t)2 * BATCH + b) * NH + h) * hs;

    __shared__ __hip_bfloat16 Ks[64][72];       // K rows      [key][d]
    __shared__ __hip_bfloat16 Vt[64][72];       // V transposed [d][key]
    __shared__ __hip_bfloat16 Ps[4][16][72];    // per-wave P   [qrow][key]

    const int tid  = threadIdx.x;
    const int wave = tid >> 6;
    const int lane = tid & 63;
    const int lr   = lane & 15;
    const int lg   = lane >> 4;

    // Q fragments (already scaled by 1/sqrt(D) at projection)
    short8 qf0, qf1;
    {
        const __hip_bfloat16* src = qp + (size_t)(qbase + wave * 16 + lr) * HD + lg * 8;
        qf0 = *(const short8*)src;          // d = lg*8..+7
        qf1 = *(const short8*)(src + 32);   // d = 32+lg*8..+7
    }

    float m_run[4] = {-1e30f, -1e30f, -1e30f, -1e30f};
    float l_run[4] = {0.f, 0.f, 0.f, 0.f};
    f32x4 o_acc[4] = {};

    for (int kt = 0; kt <= qt; ++kt) {
        const int kbase = kt * 64;
        __syncthreads();
        {   // stage K (row-major) and V (transposed)
            const int r  = tid >> 2;
            const int d0 = (tid & 3) * 16;
            const __hip_bfloat16* srcK = kp + (size_t)(kbase + r) * HD + d0;
            *(short8*)&Ks[r][d0]     = *(const short8*)srcK;
            *(short8*)&Ks[r][d0 + 8] = *(const short8*)(srcK + 8);
            const __hip_bfloat16* srcV = vp + (size_t)(kbase + r) * HD + d0;
            short8 v0 = *(const short8*)srcV;
            short8 v1 = *(const short8*)(srcV + 8);
            const __hip_bfloat16* pv0 = (const __hip_bfloat16*)&v0;
            const __hip_bfloat16* pv1 = (const __hip_bfloat16*)&v1;
            #pragma unroll
            for (int j = 0; j < 8; ++j) Vt[d0 + j][r]     = pv0[j];
            #pragma unroll
            for (int j = 0; j < 8; ++j) Vt[d0 + 8 + j][r] = pv1[j];
        }
        __syncthreads();

        // S = Q K^T : 4 col tiles of 16 keys
        f32x4 s[4];
        #pragma unroll
        for (int ct = 0; ct < 4; ++ct) {
            short8 kf0 = *(const short8*)&Ks[ct * 16 + lr][lg * 8];
            short8 kf1 = *(const short8*)&Ks[ct * 16 + lr][32 + lg * 8];
            f32x4 z = {};
            z     = __builtin_amdgcn_mfma_f32_16x16x32_bf16(qf0, kf0, z, 0, 0, 0);
            s[ct] = __builtin_amdgcn_mfma_f32_16x16x32_bf16(qf1, kf1, z, 0, 0, 0);
        }

        // causal mask + per-row max (rows live across 16-lane groups)
        const int qrow0 = qbase + wave * 16 + lg * 4;
        float tmax[4];
        #pragma unroll
        for (int i = 0; i < 4; ++i) {
            const int qrow = qrow0 + i;
            float mx = -1e30f;
            #pragma unroll
            for (int ct = 0; ct < 4; ++ct) {
                const int key = kbase + ct * 16 + lr;
                float sv = s[ct][i];
                sv = (key > qrow) ? -1e30f : sv;
                s[ct][i] = sv;
                mx = fmaxf(mx, sv);
            }
            tmax[i] = mx;
        }
        #pragma unroll
        for (int mask = 1; mask < 16; mask <<= 1) {
            #pragma unroll
            for (int i = 0; i < 4; ++i)
                tmax[i] = fmaxf(tmax[i], __shfl_xor(tmax[i], mask, 64));
        }

        // online softmax update
        #pragma unroll
        for (int i = 0; i < 4; ++i) {
            const float mnew = fmaxf(m_run[i], tmax[i]);
            const float corr = __expf(m_run[i] - mnew);
            m_run[i] = mnew;
            float rs = 0.f;
            #pragma unroll
            for (int ct = 0; ct < 4; ++ct) {
                const float p = __expf(s[ct][i] - mnew);
                s[ct][i] = p;
                rs += p;
            }
            #pragma unroll
            for (int mask = 1; mask < 16; mask <<= 1)
                rs += __shfl_xor(rs, mask, 64);
            l_run[i] = l_run[i] * corr + rs;
            #pragma unroll
            for (int ct = 0; ct < 4; ++ct)
                o_acc[ct][i] *= corr;
        }

        // P -> LDS (bf16), per-wave buffer; same-wave RAW handled by compiler waits
        #pragma unroll
        for (int ct = 0; ct < 4; ++ct) {
            #pragma unroll
            for (int i = 0; i < 4; ++i)
                Ps[wave][lg * 4 + i][ct * 16 + lr] = __float2bfloat16(s[ct][i]);
        }

        // O += P V
        short8 p0 = *(const short8*)&Ps[wave][lr][lg * 8];
        short8 p1 = *(const short8*)&Ps[wave][lr][32 + lg * 8];
        #pragma unroll
        for (int ct = 0; ct < 4; ++ct) {
            short8 vf0 = *(const short8*)&Vt[ct * 16 + lr][lg * 8];
            short8 vf1 = *(const short8*)&Vt[ct * 16 + lr][32 + lg * 8];
            o_acc[ct] = __builtin_amdgcn_mfma_f32_16x16x32_bf16(p0, vf0, o_acc[ct], 0, 0, 0);
            o_acc[ct] = __builtin_amdgcn_mfma_f32_16x16x32_bf16(p1, vf1, o_acc[ct], 0, 0, 0);
        }
    }

    // epilogue: out[b][t][h*64 + d], fp32
    float* op = out + (size_t)b * SEQ * (NH * HD) + (size_t)h * HD;
    #pragma unroll
    for (int i = 0; i < 4; ++i) {
        const float inv = 1.0f / l_run[i];
        const int trow = qbase + wave * 16 + lg * 4 + i;
        #pragma unroll
        for (int ct = 0; ct < 4; ++ct)
            op[(size_t)trow * (NH * HD) + ct * 16 + lr] = o_acc[ct][i] * inv;
    }
}

extern "C" void kernel_launch(void* const* d_in, const int* in_sizes, int n_in,
                              void* d_out, int out_size, void* d_ws, size_t ws_size,
                              hipStream_t stream) {
    const float* x  = (const float*)d_in[0];
    const float* Wq = (const float*)d_in[1];
    const float* Wk = (const float*)d_in[2];
    const float* Wv = (const float*)d_in[3];
    float* out = (float*)d_out;
    __hip_bfloat16* qkv = (__hip_bfloat16*)d_ws;   // [3][B][H][T][D] bf16, ~50 MB

    dim3 gridP((BATCH * SEQ) / 64, 3 * NH);
    hipLaunchKernelGGL(qkv_proj_kernel, gridP, dim3(256), 0, stream, x, Wq, Wk, Wv, qkv);

    dim3 gridA(SEQ / 64, NH, BATCH);
    hipLaunchKernelGGL(attn_kernel, gridA, dim3(256), 0, stream, qkv, out);
}

// Round 2
// 385.539 us; speedup vs baseline: 1.1517x; 1.1517x over previous
//
#include <hip/hip_runtime.h>
#include <hip/hip_bf16.h>

#define BATCH 4
#define SEQ   2048
#define EMB   1024
#define NH    16
#define HD    64

// workspace element offsets (bf16 elems). total 28,311,552 elems = 56.6 MB
#define Q_OFF  ((size_t)0)           // q  [B][H][T][D], pre-scaled by 0.125
#define K_OFF  ((size_t)8388608)     // k  [B][H][T][D]
#define V_OFF  ((size_t)16777216)    // vT [B][H][D][T]
#define WT_OFF ((size_t)25165824)    // Wt [3*H][D][E]

typedef __attribute__((ext_vector_type(8))) short short8;   // 8 bf16
typedef __attribute__((ext_vector_type(4))) float f32x4;    // MFMA acc

__device__ __forceinline__ short8 pack8(float4 a, float4 b) {
    alignas(16) __hip_bfloat16 t[8] = {
        __float2bfloat16(a.x), __float2bfloat16(a.y),
        __float2bfloat16(a.z), __float2bfloat16(a.w),
        __float2bfloat16(b.x), __float2bfloat16(b.y),
        __float2bfloat16(b.z), __float2bfloat16(b.w)};
    return *reinterpret_cast<const short8*>(t);
}

// ---------------------------------------------------------------------------
// Kernel 0: one-shot W transpose+cast: W[h][e][d] fp32 -> Wt[mh][d][e] bf16
// ---------------------------------------------------------------------------
__global__ __launch_bounds__(256)
void wt_kernel(const float* __restrict__ Wq, const float* __restrict__ Wk,
               const float* __restrict__ Wv, __hip_bfloat16* __restrict__ Wt)
{
    const int et = blockIdx.x;               // 16 e-tiles of 64
    const int mh = blockIdx.y;               // 48
    const int m = mh >> 4, h = mh & 15;
    const float* W = ((m == 0) ? Wq : (m == 1) ? Wk : Wv) + (size_t)h * (EMB * HD);

    __shared__ __hip_bfloat16 T[64][72];     // [d][e-local]
    const int tid = threadIdx.x;
    const int r   = tid >> 2;                // 0..63
    const int seg = (tid & 3) * 16;

    {   // read rows e = et*64 + r, d-seg
        const float* src = W + (size_t)(et * 64 + r) * HD + seg;
        float4 f0 = ((const float4*)src)[0];
        float4 f1 = ((const float4*)src)[1];
        float4 f2 = ((const float4*)src)[2];
        float4 f3 = ((const float4*)src)[3];
        const float v[16] = {f0.x,f0.y,f0.z,f0.w, f1.x,f1.y,f1.z,f1.w,
                             f2.x,f2.y,f2.z,f2.w, f3.x,f3.y,f3.z,f3.w};
        #pragma unroll
        for (int j = 0; j < 16; ++j) T[seg + j][r] = __float2bfloat16(v[j]);
    }
    __syncthreads();
    // write row d = r, e-seg: coalesced
    __hip_bfloat16* dst = Wt + ((size_t)mh * HD + r) * EMB + et * 64 + seg;
    *(short8*)dst       = *(const short8*)&T[r][seg];
    *(short8*)(dst + 8) = *(const short8*)&T[r][seg + 8];
}

// ---------------------------------------------------------------------------
// Kernel 1: fused QKV projection, 128-row x 64-col tiles, BK=64, 4 waves.
// A staged fp32->bf16 vectorized; B staged as short8 rows from Wt.
// Register prefetch (T14) of next k-tile. V written transposed via LDS bounce.
// ---------------------------------------------------------------------------
__global__ __launch_bounds__(256)
void qkv_proj_kernel(const float* __restrict__ x,
                     const __hip_bfloat16* __restrict__ Wt,
                     __hip_bfloat16* __restrict__ qkv)
{
    const int mh      = blockIdx.x;          // 48 (fastest: 48%8==0 -> W stays per-XCD)
    const int rowTile = blockIdx.y;          // 64 tiles of 128 rows
    const int m = mh >> 4, h = mh & 15;
    const int row0 = rowTile * 128;

    __shared__ __hip_bfloat16 As[128][72];   // x tile [row][k]
    __shared__ __hip_bfloat16 Bs[64][72];    // Wt tile [d][k]

    const int tid  = threadIdx.x;
    const int wave = tid >> 6;
    const int lane = tid & 63;
    const int lr   = lane & 15;
    const int lg   = lane >> 4;

    const __hip_bfloat16* Wp = Wt + (size_t)mh * (HD * EMB);   // [d][e]

    const int ar = tid >> 1;                 // 0..127
    const int ac = (tid & 1) * 32;           // 0 or 32
    const int br = tid >> 2;                 // 0..63
    const int bc = (tid & 3) * 16;

    f32x4 acc[2][4] = {};

    float4 af[8];
    short8 bp0, bp1;

    // prologue: load k-tile 0 into regs, stage, barrier
    {
        const float* srcA = x + (size_t)(row0 + ar) * EMB + ac;
        #pragma unroll
        for (int q = 0; q < 8; ++q) af[q] = ((const float4*)srcA)[q];
        const __hip_bfloat16* srcB = Wp + (size_t)br * EMB + bc;
        bp0 = *(const short8*)srcB;
        bp1 = *(const short8*)(srcB + 8);
    }
    #pragma unroll
    for (int q = 0; q < 4; ++q)
        *(short8*)&As[ar][ac + q * 8] = pack8(af[q * 2], af[q * 2 + 1]);
    *(short8*)&Bs[br][bc]     = bp0;
    *(short8*)&Bs[br][bc + 8] = bp1;
    __syncthreads();

    for (int k0 = 0; k0 < EMB; k0 += 64) {
        const bool more = (k0 + 64 < EMB);
        if (more) {   // prefetch next k-tile into regs (issue before compute)
            const float* srcA = x + (size_t)(row0 + ar) * EMB + (k0 + 64 + ac);
            #pragma unroll
            for (int q = 0; q < 8; ++q) af[q] = ((const float4*)srcA)[q];
            const __hip_bfloat16* srcB = Wp + (size_t)br * EMB + (k0 + 64 + bc);
            bp0 = *(const short8*)srcB;
            bp1 = *(const short8*)(srcB + 8);
        }
        #pragma unroll
        for (int half = 0; half < 2; ++half) {
            short8 a0 = *(const short8*)&As[wave * 32 + lr][half * 32 + lg * 8];
            short8 a1 = *(const short8*)&As[wave * 32 + 16 + lr][half * 32 + lg * 8];
            #pragma unroll
            for (int ct = 0; ct < 4; ++ct) {
                short8 bf = *(const short8*)&Bs[ct * 16 + lr][half * 32 + lg * 8];
                acc[0][ct] = __builtin_amdgcn_mfma_f32_16x16x32_bf16(a0, bf, acc[0][ct], 0, 0, 0);
                acc[1][ct] = __builtin_amdgcn_mfma_f32_16x16x32_bf16(a1, bf, acc[1][ct], 0, 0, 0);
            }
        }
        __syncthreads();
        if (more) {
            #pragma unroll
            for (int q = 0; q < 4; ++q)
                *(short8*)&As[ar][ac + q * 8] = pack8(af[q * 2], af[q * 2 + 1]);
            *(short8*)&Bs[br][bc]     = bp0;
            *(short8*)&Bs[br][bc + 8] = bp1;
            __syncthreads();
        }
    }

    // epilogue. C/D layout: col=lane&15, row=(lane>>4)*4+i
    const int b   = row0 / SEQ;
    const int tl0 = (row0 % SEQ) + wave * 32;
    if (m < 2) {
        const float scale = (m == 0) ? 0.125f : 1.0f;
        __hip_bfloat16* outp = qkv + ((m == 0) ? Q_OFF : K_OFF)
                             + ((size_t)b * NH + h) * (SEQ * HD);
        #pragma unroll
        for (int rsub = 0; rsub < 2; ++rsub)
            #pragma unroll
            for (int ct = 0; ct < 4; ++ct)
                #pragma unroll
                for (int i = 0; i < 4; ++i) {
                    const int trow = tl0 + rsub * 16 + lg * 4 + i;
                    outp[(size_t)trow * HD + ct * 16 + lr] =
                        __float2bfloat16(acc[rsub][ct][i] * scale);
                }
    } else {
        // V: transpose 128t x 64d tile via LDS, write vT[b][h][d][t] coalesced
        __hip_bfloat16 (*Ts)[136] = (__hip_bfloat16(*)[136])&As[0][0];  // 64x136 fits
        __syncthreads();   // done with As reads from GEMM loop
        #pragma unroll
        for (int rsub = 0; rsub < 2; ++rsub)
            #pragma unroll
            for (int ct = 0; ct < 4; ++ct)
                #pragma unroll
                for (int i = 0; i < 4; ++i)
                    Ts[ct * 16 + lr][wave * 32 + rsub * 16 + lg * 4 + i] =
                        __float2bfloat16(acc[rsub][ct][i]);
        __syncthreads();
        const int d    = tid >> 2;
        const int tseg = (tid & 3) * 32;
        __hip_bfloat16* dst = qkv + V_OFF + ((size_t)b * NH + h) * (HD * SEQ)
                            + (size_t)d * SEQ + (row0 % SEQ) + tseg;
        #pragma unroll
        for (int q = 0; q < 4; ++q)
            *(short8*)(dst + q * 8) = *(const short8*)&Ts[d][tseg + q * 8];
    }
}

// ---------------------------------------------------------------------------
// Kernel 2: causal flash attention. 128 q-rows/block, 4 waves x 32 rows.
// KV tiles of 64, register prefetch, V read pre-transposed. XCD swizzle.
// ---------------------------------------------------------------------------
__global__ __launch_bounds__(256)
void attn_kernel(const __hip_bfloat16* __restrict__ ws, float* __restrict__ out)
{
    const int bid     = blockIdx.x;                   // 1024
    const int logical = (bid & 7) * 128 + (bid >> 3); // bijective XCD chunking
    const int qt = logical & 15;
    const int h  = (logical >> 4) & 15;
    const int b  = logical >> 8;
    const int qbase = qt * 128;

    const __hip_bfloat16* qp = ws + Q_OFF + ((size_t)b * NH + h) * (SEQ * HD);
    const __hip_bfloat16* kp = ws + K_OFF + ((size_t)b * NH + h) * (SEQ * HD);
    const __hip_bfloat16* vt = ws + V_OFF + ((size_t)b * NH + h) * (HD * SEQ); // [d][t]

    __shared__ __hip_bfloat16 Ks[64][72];        // [key][d]
    __shared__ __hip_bfloat16 Vs[64][72];        // [d][key]
    __shared__ __hip_bfloat16 Ps[4][16][72];     // per-wave P [qrow][key]

    const int tid  = threadIdx.x;
    const int wave = tid >> 6;
    const int lane = tid & 63;
    const int lr   = lane & 15;
    const int lg   = lane >> 4;

    // Q fragments: rows qbase + wave*32 + rsub*16 + lr  (Q pre-scaled 0.125)
    short8 qf[2][2];
    #pragma unroll
    for (int rsub = 0; rsub < 2; ++rsub) {
        const __hip_bfloat16* src =
            qp + (size_t)(qbase + wave * 32 + rsub * 16 + lr) * HD + lg * 8;
        qf[rsub][0] = *(const short8*)src;
        qf[rsub][1] = *(const short8*)(src + 32);
    }

    float m_run[2][4], l_run[2][4];
    f32x4 o_acc[2][4] = {};
    #pragma unroll
    for (int r = 0; r < 2; ++r)
        #pragma unroll
        for (int i = 0; i < 4; ++i) { m_run[r][i] = -1e30f; l_run[r][i] = 0.f; }

    const int ktmax = 2 * qt + 1;
    const int sr = tid >> 2;            // stage row 0..63
    const int sc = (tid & 3) * 16;      // stage col seg

    // prologue: stage tile 0
    short8 kr0, kr1, vr0, vr1;
    kr0 = *(const short8*)(kp + (size_t)sr * HD + sc);
    kr1 = *(const short8*)(kp + (size_t)sr * HD + sc + 8);
    vr0 = *(const short8*)(vt + (size_t)sr * SEQ + sc);
    vr1 = *(const short8*)(vt + (size_t)sr * SEQ + sc + 8);
    *(short8*)&Ks[sr][sc]     = kr0;
    *(short8*)&Ks[sr][sc + 8] = kr1;
    *(short8*)&Vs[sr][sc]     = vr0;
    *(short8*)&Vs[sr][sc + 8] = vr1;
    __syncthreads();

    for (int kt = 0; kt <= ktmax; ++kt) {
        const int kbase = kt * 64;
        if (kt < ktmax) {   // prefetch next K/V tile into regs
            const int nb = kbase + 64;
            kr0 = *(const short8*)(kp + (size_t)(nb + sr) * HD + sc);
            kr1 = *(const short8*)(kp + (size_t)(nb + sr) * HD + sc + 8);
            vr0 = *(const short8*)(vt + (size_t)sr * SEQ + nb + sc);
            vr1 = *(const short8*)(vt + (size_t)sr * SEQ + nb + sc + 8);
        }

        // S = Q K^T
        f32x4 s[2][4];
        #pragma unroll
        for (int ct = 0; ct < 4; ++ct) {
            short8 kf0 = *(const short8*)&Ks[ct * 16 + lr][lg * 8];
            short8 kf1 = *(const short8*)&Ks[ct * 16 + lr][32 + lg * 8];
            #pragma unroll
            for (int rsub = 0; rsub < 2; ++rsub) {
                f32x4 z = {};
                z            = __builtin_amdgcn_mfma_f32_16x16x32_bf16(qf[rsub][0], kf0, z, 0, 0, 0);
                s[rsub][ct]  = __builtin_amdgcn_mfma_f32_16x16x32_bf16(qf[rsub][1], kf1, z, 0, 0, 0);
            }
        }

        // causal mask (only the two diagonal tiles need it)
        if (kt >= 2 * qt) {
            #pragma unroll
            for (int rsub = 0; rsub < 2; ++rsub)
                #pragma unroll
                for (int i = 0; i < 4; ++i) {
                    const int qrow = qbase + wave * 32 + rsub * 16 + lg * 4 + i;
                    #pragma unroll
                    for (int ct = 0; ct < 4; ++ct) {
                        const int key = kbase + ct * 16 + lr;
                        s[rsub][ct][i] = (key > qrow) ? -1e30f : s[rsub][ct][i];
                    }
                }
        }

        // online softmax + PV per rsub
        #pragma unroll
        for (int rsub = 0; rsub < 2; ++rsub) {
            float tmax[4];
            #pragma unroll
            for (int i = 0; i < 4; ++i)
                tmax[i] = fmaxf(fmaxf(s[rsub][0][i], s[rsub][1][i]),
                                fmaxf(s[rsub][2][i], s[rsub][3][i]));
            #pragma unroll
            for (int mask = 1; mask < 16; mask <<= 1)
                #pragma unroll
                for (int i = 0; i < 4; ++i)
                    tmax[i] = fmaxf(tmax[i], __shfl_xor(tmax[i], mask, 64));

            #pragma unroll
            for (int i = 0; i < 4; ++i) {
                const float mnew = fmaxf(m_run[rsub][i], tmax[i]);
                const float corr = __expf(m_run[rsub][i] - mnew);
                m_run[rsub][i] = mnew;
                float rs = 0.f;
                #pragma unroll
                for (int ct = 0; ct < 4; ++ct) {
                    const float p = __expf(s[rsub][ct][i] - mnew);
                    s[rsub][ct][i] = p;
                    rs += p;
                }
                #pragma unroll
                for (int mask = 1; mask < 16; mask <<= 1)
                    rs += __shfl_xor(rs, mask, 64);
                l_run[rsub][i] = l_run[rsub][i] * corr + rs;
                #pragma unroll
                for (int ct = 0; ct < 4; ++ct)
                    o_acc[rsub][ct][i] *= corr;
            }

            // P -> LDS (per-wave buffer), then PV
            #pragma unroll
            for (int ct = 0; ct < 4; ++ct)
                #pragma unroll
                for (int i = 0; i < 4; ++i)
                    Ps[wave][lg * 4 + i][ct * 16 + lr] = __float2bfloat16(s[rsub][ct][i]);

            short8 pa0 = *(const short8*)&Ps[wave][lr][lg * 8];
            short8 pa1 = *(const short8*)&Ps[wave][lr][32 + lg * 8];
            #pragma unroll
            for (int ct = 0; ct < 4; ++ct) {
                short8 vf0 = *(const short8*)&Vs[ct * 16 + lr][lg * 8];
                short8 vf1 = *(const short8*)&Vs[ct * 16 + lr][32 + lg * 8];
                o_acc[rsub][ct] = __builtin_amdgcn_mfma_f32_16x16x32_bf16(pa0, vf0, o_acc[rsub][ct], 0, 0, 0);
                o_acc[rsub][ct] = __builtin_amdgcn_mfma_f32_16x16x32_bf16(pa1, vf1, o_acc[rsub][ct], 0, 0, 0);
            }
        }

        __syncthreads();                 // all waves done reading Ks/Vs
        if (kt < ktmax) {
            *(short8*)&Ks[sr][sc]     = kr0;
            *(short8*)&Ks[sr][sc + 8] = kr1;
            *(short8*)&Vs[sr][sc]     = vr0;
            *(short8*)&Vs[sr][sc + 8] = vr1;
            __syncthreads();
        }
    }

    // epilogue: out[b][t][h*64 + d] fp32
    float* op = out + (size_t)b * SEQ * (NH * HD) + (size_t)h * HD;
    #pragma unroll
    for (int rsub = 0; rsub < 2; ++rsub)
        #pragma unroll
        for (int i = 0; i < 4; ++i) {
            const float inv  = 1.0f / l_run[rsub][i];
            const int   trow = qbase + wave * 32 + rsub * 16 + lg * 4 + i;
            #pragma unroll
            for (int ct = 0; ct < 4; ++ct)
                op[(size_t)trow * (NH * HD) + ct * 16 + lr] = o_acc[rsub][ct][i] * inv;
        }
}

extern "C" void kernel_launch(void* const* d_in, const int* in_sizes, int n_in,
                              void* d_out, int out_size, void* d_ws, size_t ws_size,
                              hipStream_t stream) {
    const float* x  = (const float*)d_in[0];
    const float* Wq = (const float*)d_in[1];
    const float* Wk = (const float*)d_in[2];
    const float* Wv = (const float*)d_in[3];
    float* out = (float*)d_out;
    __hip_bfloat16* ws = (__hip_bfloat16*)d_ws;

    hipLaunchKernelGGL(wt_kernel, dim3(16, 48), dim3(256), 0, stream,
                       Wq, Wk, Wv, ws + WT_OFF);
    hipLaunchKernelGGL(qkv_proj_kernel, dim3(48, 64), dim3(256), 0, stream,
                       x, ws + WT_OFF, ws);
    hipLaunchKernelGGL(attn_kernel, dim3(1024), dim3(256), 0, stream, ws, out);
}

// Round 3
// 266.035 us; speedup vs baseline: 1.6690x; 1.4492x over previous
//
#include <hip/hip_runtime.h>
#include <hip/hip_bf16.h>

#define BATCH 4
#define SEQ   2048
#define EMB   1024
#define NH    16
#define HD    64

// workspace bf16-element offsets (total 28,311,552 elems = 56.6 MB)
#define Q_OFF  ((size_t)0)           // q  [B][H][T][D]  (scale folded into Wq)
#define K_OFF  ((size_t)8388608)     // k  [B][H][T][D]
#define V_OFF  ((size_t)16777216)    // vT [B][H][D][T]
#define WT_OFF ((size_t)25165824)    // Wt [3072][1024] = [mh*64+d][e], Wq rows pre-scaled

typedef __attribute__((ext_vector_type(8))) short short8;   // 8 bf16
typedef __attribute__((ext_vector_type(4))) float f32x4;    // MFMA acc

__device__ __forceinline__ short8 pack8s(float4 a, float4 b, float s) {
    alignas(16) __hip_bfloat16 t[8] = {
        __float2bfloat16(a.x * s), __float2bfloat16(a.y * s),
        __float2bfloat16(a.z * s), __float2bfloat16(a.w * s),
        __float2bfloat16(b.x * s), __float2bfloat16(b.y * s),
        __float2bfloat16(b.z * s), __float2bfloat16(b.w * s)};
    return *reinterpret_cast<const short8*>(t);
}

// async global->LDS, 16B per lane. LDS dest is wave-uniform base + lane*16.
__device__ __forceinline__ void async16(void* lds, const void* g) {
    __builtin_amdgcn_global_load_lds(
        (const __attribute__((address_space(1))) unsigned int*)g,
        (__attribute__((address_space(3))) unsigned int*)lds, 16, 0, 0);
}

// ---------------------------------------------------------------------------
// Kernel A: x fp32 -> bf16 (linear). Output lives in d_out (overwritten later).
// ---------------------------------------------------------------------------
__global__ __launch_bounds__(256)
void xcast_kernel(const float* __restrict__ x, __hip_bfloat16* __restrict__ xb)
{
    const size_t i = ((size_t)blockIdx.x * 256 + threadIdx.x) * 8;
    float4 f0 = ((const float4*)(x + i))[0];
    float4 f1 = ((const float4*)(x + i))[1];
    *(short8*)(xb + i) = pack8s(f0, f1, 1.0f);
}

// ---------------------------------------------------------------------------
// Kernel B: W transpose+cast: W[h][e][d] fp32 -> Wt[mh*64+d][e] bf16.
// Wq rows scaled by 0.125 (exact pow2 -> no extra rounding error).
// ---------------------------------------------------------------------------
__global__ __launch_bounds__(256)
void wt_kernel(const float* __restrict__ Wq, const float* __restrict__ Wk,
               const float* __restrict__ Wv, __hip_bfloat16* __restrict__ Wt)
{
    const int et = blockIdx.x;               // 16 e-tiles of 64
    const int mh = blockIdx.y;               // 48
    const int m = mh >> 4, h = mh & 15;
    const float* W = ((m == 0) ? Wq : (m == 1) ? Wk : Wv) + (size_t)h * (EMB * HD);
    const float scale = (m == 0) ? 0.125f : 1.0f;

    __shared__ __hip_bfloat16 T[64][72];     // [d][e-local]
    const int tid = threadIdx.x;
    const int r   = tid >> 2;                // 0..63
    const int seg = (tid & 3) * 16;

    {
        const float* src = W + (size_t)(et * 64 + r) * HD + seg;
        float4 f0 = ((const float4*)src)[0];
        float4 f1 = ((const float4*)src)[1];
        float4 f2 = ((const float4*)src)[2];
        float4 f3 = ((const float4*)src)[3];
        const float v[16] = {f0.x,f0.y,f0.z,f0.w, f1.x,f1.y,f1.z,f1.w,
                             f2.x,f2.y,f2.z,f2.w, f3.x,f3.y,f3.z,f3.w};
        #pragma unroll
        for (int j = 0; j < 16; ++j) T[seg + j][r] = __float2bfloat16(v[j] * scale);
    }
    __syncthreads();
    __hip_bfloat16* dst = Wt + ((size_t)mh * HD + r) * EMB + et * 64 + seg;
    *(short8*)dst       = *(const short8*)&T[r][seg];
    *(short8*)(dst + 8) = *(const short8*)&T[r][seg + 8];
}

// ---------------------------------------------------------------------------
// Kernel 1: QKV projection as bf16 GEMM, m97 structure.
// C[8192][3072] = xb[8192][1024] . Wt^T ; 128x128 tiles, BK=64, 4 waves.
// global_load_lds(16B) staging, XOR-swizzled LDS (T2, both-sides).
// LDS[r][j] holds A[r][j ^ (r&7)] (j = 16B slot 0..7 within 64-elem k window).
// ---------------------------------------------------------------------------
__global__ __launch_bounds__(256)
void qkv_proj_kernel(const __hip_bfloat16* __restrict__ xb,   // [8192][1024]
                     const __hip_bfloat16* __restrict__ Wt,   // [3072][1024]
                     __hip_bfloat16* __restrict__ qkv)
{
    const int nt = blockIdx.x;               // 0..23 col tiles (2 heads each)
    const int rt = blockIdx.y;               // 0..63 row tiles
    const int row0 = rt * 128;
    const int n0   = nt * 128;

    __shared__ __hip_bfloat16 lds[17408];    // As[0..8191], Bs[8192..16383]; V-bounce reuses all
    __hip_bfloat16* As = lds;                // [128][64] swizzled, row=128B
    __hip_bfloat16* Bs = lds + 8192;         // [128][64] swizzled (rows = C cols)

    const int tid  = threadIdx.x;
    const int wave = tid >> 6;
    const int lane = tid & 63;
    const int lr   = lane & 15;
    const int lg   = lane >> 4;

    // staging geometry: one issue = 8 rows x 128B; lane l -> row +(l>>3), slot l&7.
    // source pre-swizzle: fetch slot (l&7)^(l>>3) so LDS[r][j] = A[r][j^(r&7)].
    const int srow  = lane >> 3;
    const int sslot = (lane & 7) ^ srow;
    const char* aSrc = (const char*)xb + (size_t)(row0 + wave * 32 + srow) * 2048 + sslot * 16;
    const char* bSrc = (const char*)Wt + (size_t)(n0   + wave * 32 + srow) * 2048 + sslot * 16;
    char* aDst = (char*)As + (size_t)(wave * 32) * 128;
    char* bDst = (char*)Bs + (size_t)(wave * 32) * 128;

    f32x4 acc[2][8] = {};

    for (int k0 = 0; k0 < EMB; k0 += 64) {
        __syncthreads();
        #pragma unroll
        for (int i = 0; i < 4; ++i) {
            async16(aDst + i * 1024, aSrc + (size_t)i * 16384 + k0 * 2);
            async16(bDst + i * 1024, bSrc + (size_t)i * 16384 + k0 * 2);
        }
        __syncthreads();

        #pragma unroll
        for (int half = 0; half < 2; ++half) {
            const int cg = half * 4 + lg;                     // k slot 0..7
            const int r0a = wave * 32 + lr;
            const int r1a = wave * 32 + 16 + lr;
            short8 a0 = *(const short8*)((char*)As + r0a * 128 + ((cg ^ (r0a & 7)) * 16));
            short8 a1 = *(const short8*)((char*)As + r1a * 128 + ((cg ^ (r1a & 7)) * 16));
            #pragma unroll
            for (int ct = 0; ct < 8; ++ct) {
                const int rb = ct * 16 + lr;
                short8 bf = *(const short8*)((char*)Bs + rb * 128 + ((cg ^ (rb & 7)) * 16));
                acc[0][ct] = __builtin_amdgcn_mfma_f32_16x16x32_bf16(a0, bf, acc[0][ct], 0, 0, 0);
                acc[1][ct] = __builtin_amdgcn_mfma_f32_16x16x32_bf16(a1, bf, acc[1][ct], 0, 0, 0);
            }
        }
    }

    // epilogue. C/D: col = lane&15, row = (lane>>4)*4 + i.
    const int m   = n0 >> 10;                 // 0,1,2
    const int b   = row0 >> 11;
    const int tl0 = (row0 & (SEQ - 1)) + wave * 32;
    if (m < 2) {
        __hip_bfloat16* outp = qkv + ((m == 0) ? Q_OFF : K_OFF)
                             + (size_t)b * NH * SEQ * HD;
        #pragma unroll
        for (int rsub = 0; rsub < 2; ++rsub)
            #pragma unroll
            for (int ct = 0; ct < 8; ++ct) {
                const int h = (2 * nt + (ct >> 2)) & 15;
                const int d = (ct & 3) * 16 + lr;
                #pragma unroll
                for (int i = 0; i < 4; ++i) {
                    const int trow = tl0 + rsub * 16 + lg * 4 + i;
                    outp[((size_t)h * SEQ + trow) * HD + d] = __float2bfloat16(acc[rsub][ct][i]);
                }
            }
    } else {
        // V: transpose 128t x 128c tile via LDS bounce -> vT[b][h][d][t]
        __hip_bfloat16 (*Ts)[136] = (__hip_bfloat16(*)[136])lds;   // 128*136 = 17408 ✓
        __syncthreads();
        #pragma unroll
        for (int rsub = 0; rsub < 2; ++rsub)
            #pragma unroll
            for (int ct = 0; ct < 8; ++ct)
                #pragma unroll
                for (int i = 0; i < 4; ++i)
                    Ts[ct * 16 + lr][wave * 32 + rsub * 16 + lg * 4 + i] =
                        __float2bfloat16(acc[rsub][ct][i]);
        __syncthreads();
        const int c    = tid >> 1;            // 0..127 (local col = head*64+d)
        const int tseg = (tid & 1) * 64;
        const int hv   = (2 * nt + (c >> 6)) & 15;
        const int dv   = c & 63;
        __hip_bfloat16* dst = qkv + V_OFF + ((size_t)b * NH + hv) * (HD * SEQ)
                            + (size_t)dv * SEQ + (row0 & (SEQ - 1)) + tseg;
        #pragma unroll
        for (int q = 0; q < 8; ++q)
            *(short8*)(dst + q * 8) = *(const short8*)&Ts[c][tseg + q * 8];
    }
}

// ---------------------------------------------------------------------------
// Kernel 2: causal flash attention (unchanged from round 2).
// ---------------------------------------------------------------------------
__global__ __launch_bounds__(256)
void attn_kernel(const __hip_bfloat16* __restrict__ ws, float* __restrict__ out)
{
    const int bid     = blockIdx.x;                   // 1024
    const int logical = (bid & 7) * 128 + (bid >> 3); // bijective XCD chunking
    const int qt = logical & 15;
    const int h  = (logical >> 4) & 15;
    const int b  = logical >> 8;
    const int qbase = qt * 128;

    const __hip_bfloat16* qp = ws + Q_OFF + ((size_t)b * NH + h) * (SEQ * HD);
    const __hip_bfloat16* kp = ws + K_OFF + ((size_t)b * NH + h) * (SEQ * HD);
    const __hip_bfloat16* vt = ws + V_OFF + ((size_t)b * NH + h) * (HD * SEQ); // [d][t]

    __shared__ __hip_bfloat16 Ks[64][72];
    __shared__ __hip_bfloat16 Vs[64][72];
    __shared__ __hip_bfloat16 Ps[4][16][72];

    const int tid  = threadIdx.x;
    const int wave = tid >> 6;
    const int lane = tid & 63;
    const int lr   = lane & 15;
    const int lg   = lane >> 4;

    short8 qf[2][2];
    #pragma unroll
    for (int rsub = 0; rsub < 2; ++rsub) {
        const __hip_bfloat16* src =
            qp + (size_t)(qbase + wave * 32 + rsub * 16 + lr) * HD + lg * 8;
        qf[rsub][0] = *(const short8*)src;
        qf[rsub][1] = *(const short8*)(src + 32);
    }

    float m_run[2][4], l_run[2][4];
    f32x4 o_acc[2][4] = {};
    #pragma unroll
    for (int r = 0; r < 2; ++r)
        #pragma unroll
        for (int i = 0; i < 4; ++i) { m_run[r][i] = -1e30f; l_run[r][i] = 0.f; }

    const int ktmax = 2 * qt + 1;
    const int sr = tid >> 2;
    const int sc = (tid & 3) * 16;

    short8 kr0, kr1, vr0, vr1;
    kr0 = *(const short8*)(kp + (size_t)sr * HD + sc);
    kr1 = *(const short8*)(kp + (size_t)sr * HD + sc + 8);
    vr0 = *(const short8*)(vt + (size_t)sr * SEQ + sc);
    vr1 = *(const short8*)(vt + (size_t)sr * SEQ + sc + 8);
    *(short8*)&Ks[sr][sc]     = kr0;
    *(short8*)&Ks[sr][sc + 8] = kr1;
    *(short8*)&Vs[sr][sc]     = vr0;
    *(short8*)&Vs[sr][sc + 8] = vr1;
    __syncthreads();

    for (int kt = 0; kt <= ktmax; ++kt) {
        const int kbase = kt * 64;
        if (kt < ktmax) {
            const int nb = kbase + 64;
            kr0 = *(const short8*)(kp + (size_t)(nb + sr) * HD + sc);
            kr1 = *(const short8*)(kp + (size_t)(nb + sr) * HD + sc + 8);
            vr0 = *(const short8*)(vt + (size_t)sr * SEQ + nb + sc);
            vr1 = *(const short8*)(vt + (size_t)sr * SEQ + nb + sc + 8);
        }

        f32x4 s[2][4];
        #pragma unroll
        for (int ct = 0; ct < 4; ++ct) {
            short8 kf0 = *(const short8*)&Ks[ct * 16 + lr][lg * 8];
            short8 kf1 = *(const short8*)&Ks[ct * 16 + lr][32 + lg * 8];
            #pragma unroll
            for (int rsub = 0; rsub < 2; ++rsub) {
                f32x4 z = {};
                z           = __builtin_amdgcn_mfma_f32_16x16x32_bf16(qf[rsub][0], kf0, z, 0, 0, 0);
                s[rsub][ct] = __builtin_amdgcn_mfma_f32_16x16x32_bf16(qf[rsub][1], kf1, z, 0, 0, 0);
            }
        }

        if (kt >= 2 * qt) {
            #pragma unroll
            for (int rsub = 0; rsub < 2; ++rsub)
                #pragma unroll
                for (int i = 0; i < 4; ++i) {
                    const int qrow = qbase + wave * 32 + rsub * 16 + lg * 4 + i;
                    #pragma unroll
                    for (int ct = 0; ct < 4; ++ct) {
                        const int key = kbase + ct * 16 + lr;
                        s[rsub][ct][i] = (key > qrow) ? -1e30f : s[rsub][ct][i];
                    }
                }
        }

        #pragma unroll
        for (int rsub = 0; rsub < 2; ++rsub) {
            float tmax[4];
            #pragma unroll
            for (int i = 0; i < 4; ++i)
                tmax[i] = fmaxf(fmaxf(s[rsub][0][i], s[rsub][1][i]),
                                fmaxf(s[rsub][2][i], s[rsub][3][i]));
            #pragma unroll
            for (int mask = 1; mask < 16; mask <<= 1)
                #pragma unroll
                for (int i = 0; i < 4; ++i)
                    tmax[i] = fmaxf(tmax[i], __shfl_xor(tmax[i], mask, 64));

            #pragma unroll
            for (int i = 0; i < 4; ++i) {
                const float mnew = fmaxf(m_run[rsub][i], tmax[i]);
                const float corr = __expf(m_run[rsub][i] - mnew);
                m_run[rsub][i] = mnew;
                float rs = 0.f;
                #pragma unroll
                for (int ct = 0; ct < 4; ++ct) {
                    const float p = __expf(s[rsub][ct][i] - mnew);
                    s[rsub][ct][i] = p;
                    rs += p;
                }
                #pragma unroll
                for (int mask = 1; mask < 16; mask <<= 1)
                    rs += __shfl_xor(rs, mask, 64);
                l_run[rsub][i] = l_run[rsub][i] * corr + rs;
                #pragma unroll
                for (int ct = 0; ct < 4; ++ct)
                    o_acc[rsub][ct][i] *= corr;
            }

            #pragma unroll
            for (int ct = 0; ct < 4; ++ct)
                #pragma unroll
                for (int i = 0; i < 4; ++i)
                    Ps[wave][lg * 4 + i][ct * 16 + lr] = __float2bfloat16(s[rsub][ct][i]);

            short8 pa0 = *(const short8*)&Ps[wave][lr][lg * 8];
            short8 pa1 = *(const short8*)&Ps[wave][lr][32 + lg * 8];
            #pragma unroll
            for (int ct = 0; ct < 4; ++ct) {
                short8 vf0 = *(const short8*)&Vs[ct * 16 + lr][lg * 8];
                short8 vf1 = *(const short8*)&Vs[ct * 16 + lr][32 + lg * 8];
                o_acc[rsub][ct] = __builtin_amdgcn_mfma_f32_16x16x32_bf16(pa0, vf0, o_acc[rsub][ct], 0, 0, 0);
                o_acc[rsub][ct] = __builtin_amdgcn_mfma_f32_16x16x32_bf16(pa1, vf1, o_acc[rsub][ct], 0, 0, 0);
            }
        }

        __syncthreads();
        if (kt < ktmax) {
            *(short8*)&Ks[sr][sc]     = kr0;
            *(short8*)&Ks[sr][sc + 8] = kr1;
            *(short8*)&Vs[sr][sc]     = vr0;
            *(short8*)&Vs[sr][sc + 8] = vr1;
            __syncthreads();
        }
    }

    float* op = out + (size_t)b * SEQ * (NH * HD) + (size_t)h * HD;
    #pragma unroll
    for (int rsub = 0; rsub < 2; ++rsub)
        #pragma unroll
        for (int i = 0; i < 4; ++i) {
            const float inv  = 1.0f / l_run[rsub][i];
            const int   trow = qbase + wave * 32 + rsub * 16 + lg * 4 + i;
            #pragma unroll
            for (int ct = 0; ct < 4; ++ct)
                op[(size_t)trow * (NH * HD) + ct * 16 + lr] = o_acc[rsub][ct][i] * inv;
        }
}

extern "C" void kernel_launch(void* const* d_in, const int* in_sizes, int n_in,
                              void* d_out, int out_size, void* d_ws, size_t ws_size,
                              hipStream_t stream) {
    const float* x  = (const float*)d_in[0];
    const float* Wq = (const float*)d_in[1];
    const float* Wk = (const float*)d_in[2];
    const float* Wv = (const float*)d_in[3];
    float* out = (float*)d_out;
    __hip_bfloat16* ws = (__hip_bfloat16*)d_ws;

    // xb (bf16 x) lives in d_out's first 16.8 MB; attn fully overwrites d_out later.
    __hip_bfloat16* xb = (__hip_bfloat16*)d_out;

    hipLaunchKernelGGL(xcast_kernel, dim3((BATCH * SEQ * EMB) / (256 * 8)), dim3(256),
                       0, stream, x, xb);
    hipLaunchKernelGGL(wt_kernel, dim3(16, 48), dim3(256), 0, stream,
                       Wq, Wk, Wv, ws + WT_OFF);
    hipLaunchKernelGGL(qkv_proj_kernel, dim3(24, 64), dim3(256), 0, stream,
                       xb, ws + WT_OFF, ws);
    hipLaunchKernelGGL(attn_kernel, dim3(1024), dim3(256), 0, stream, ws, out);
}

// Round 4
// 160.977 us; speedup vs baseline: 2.7582x; 1.6526x over previous
//
#include <hip/hip_runtime.h>
#include <hip/hip_bf16.h>

#define BATCH 4
#define SEQ   2048
#define EMB   1024
#define NH    16
#define HD    64

// workspace bf16-element offsets (total 28,311,552 elems = 56.6 MB)
#define Q_OFF  ((size_t)0)           // q  [B][H][T][D]  (0.125*log2e folded into Wq)
#define K_OFF  ((size_t)8388608)     // k  [B][H][T][D]
#define V_OFF  ((size_t)16777216)    // vT [B][H][D][T]
#define WT_OFF ((size_t)25165824)    // Wt [3072][1024] = [mh*64+d][e]

typedef __attribute__((ext_vector_type(8))) short short8;   // 8 bf16
typedef __attribute__((ext_vector_type(4))) short short4v;  // 4 bf16 (8B)
typedef __attribute__((ext_vector_type(4))) float f32x4;    // MFMA acc

__device__ __forceinline__ short8 pack8s(float4 a, float4 b, float s) {
    alignas(16) __hip_bfloat16 t[8] = {
        __float2bfloat16(a.x * s), __float2bfloat16(a.y * s),
        __float2bfloat16(a.z * s), __float2bfloat16(a.w * s),
        __float2bfloat16(b.x * s), __float2bfloat16(b.y * s),
        __float2bfloat16(b.z * s), __float2bfloat16(b.w * s)};
    return *reinterpret_cast<const short8*>(t);
}

// async global->LDS, 16B per lane. LDS dest is wave-uniform base + lane*16.
__device__ __forceinline__ void async16(void* lds, const void* g) {
    __builtin_amdgcn_global_load_lds(
        (const __attribute__((address_space(1))) unsigned int*)g,
        (__attribute__((address_space(3))) unsigned int*)lds, 16, 0, 0);
}

// ---------------------------------------------------------------------------
// Kernel A: x fp32 -> bf16 (linear). Output lives in d_out (overwritten later).
// ---------------------------------------------------------------------------
__global__ __launch_bounds__(256)
void xcast_kernel(const float* __restrict__ x, __hip_bfloat16* __restrict__ xb)
{
    const size_t i = ((size_t)blockIdx.x * 256 + threadIdx.x) * 8;
    float4 f0 = ((const float4*)(x + i))[0];
    float4 f1 = ((const float4*)(x + i))[1];
    *(short8*)(xb + i) = pack8s(f0, f1, 1.0f);
}

// ---------------------------------------------------------------------------
// Kernel B: W transpose+cast: W[h][e][d] fp32 -> Wt[mh*64+d][e] bf16.
// Wq rows scaled by 0.125*log2(e): attention softmax runs in log2 domain.
// ---------------------------------------------------------------------------
__global__ __launch_bounds__(256)
void wt_kernel(const float* __restrict__ Wq, const float* __restrict__ Wk,
               const float* __restrict__ Wv, __hip_bfloat16* __restrict__ Wt)
{
    const int et = blockIdx.x;               // 16 e-tiles of 64
    const int mh = blockIdx.y;               // 48
    const int m = mh >> 4, h = mh & 15;
    const float* W = ((m == 0) ? Wq : (m == 1) ? Wk : Wv) + (size_t)h * (EMB * HD);
    const float scale = (m == 0) ? 0.18033688011112042f : 1.0f;  // 0.125*log2(e)

    __shared__ __hip_bfloat16 T[64][72];     // [d][e-local]
    const int tid = threadIdx.x;
    const int r   = tid >> 2;                // 0..63
    const int seg = (tid & 3) * 16;

    {
        const float* src = W + (size_t)(et * 64 + r) * HD + seg;
        float4 f0 = ((const float4*)src)[0];
        float4 f1 = ((const float4*)src)[1];
        float4 f2 = ((const float4*)src)[2];
        float4 f3 = ((const float4*)src)[3];
        const float v[16] = {f0.x,f0.y,f0.z,f0.w, f1.x,f1.y,f1.z,f1.w,
                             f2.x,f2.y,f2.z,f2.w, f3.x,f3.y,f3.z,f3.w};
        #pragma unroll
        for (int j = 0; j < 16; ++j) T[seg + j][r] = __float2bfloat16(v[j] * scale);
    }
    __syncthreads();
    __hip_bfloat16* dst = Wt + ((size_t)mh * HD + r) * EMB + et * 64 + seg;
    *(short8*)dst       = *(const short8*)&T[r][seg];
    *(short8*)(dst + 8) = *(const short8*)&T[r][seg + 8];
}

// ---------------------------------------------------------------------------
// Kernel 1: QKV projection as bf16 GEMM (m97 structure) — unchanged from r3.
// ---------------------------------------------------------------------------
__global__ __launch_bounds__(256)
void qkv_proj_kernel(const __hip_bfloat16* __restrict__ xb,   // [8192][1024]
                     const __hip_bfloat16* __restrict__ Wt,   // [3072][1024]
                     __hip_bfloat16* __restrict__ qkv)
{
    const int nt = blockIdx.x;               // 0..23 col tiles (2 heads each)
    const int rt = blockIdx.y;               // 0..63 row tiles
    const int row0 = rt * 128;
    const int n0   = nt * 128;

    __shared__ __hip_bfloat16 lds[17408];
    __hip_bfloat16* As = lds;                // [128][64] swizzled, row=128B
    __hip_bfloat16* Bs = lds + 8192;         // [128][64] swizzled

    const int tid  = threadIdx.x;
    const int wave = tid >> 6;
    const int lane = tid & 63;
    const int lr   = lane & 15;
    const int lg   = lane >> 4;

    const int srow  = lane >> 3;
    const int sslot = (lane & 7) ^ srow;
    const char* aSrc = (const char*)xb + (size_t)(row0 + wave * 32 + srow) * 2048 + sslot * 16;
    const char* bSrc = (const char*)Wt + (size_t)(n0   + wave * 32 + srow) * 2048 + sslot * 16;
    char* aDst = (char*)As + (size_t)(wave * 32) * 128;
    char* bDst = (char*)Bs + (size_t)(wave * 32) * 128;

    f32x4 acc[2][8] = {};

    for (int k0 = 0; k0 < EMB; k0 += 64) {
        __syncthreads();
        #pragma unroll
        for (int i = 0; i < 4; ++i) {
            async16(aDst + i * 1024, aSrc + (size_t)i * 16384 + k0 * 2);
            async16(bDst + i * 1024, bSrc + (size_t)i * 16384 + k0 * 2);
        }
        __syncthreads();

        #pragma unroll
        for (int half = 0; half < 2; ++half) {
            const int cg = half * 4 + lg;
            const int r0a = wave * 32 + lr;
            const int r1a = wave * 32 + 16 + lr;
            short8 a0 = *(const short8*)((char*)As + r0a * 128 + ((cg ^ (r0a & 7)) * 16));
            short8 a1 = *(const short8*)((char*)As + r1a * 128 + ((cg ^ (r1a & 7)) * 16));
            #pragma unroll
            for (int ct = 0; ct < 8; ++ct) {
                const int rb = ct * 16 + lr;
                short8 bf = *(const short8*)((char*)Bs + rb * 128 + ((cg ^ (rb & 7)) * 16));
                acc[0][ct] = __builtin_amdgcn_mfma_f32_16x16x32_bf16(a0, bf, acc[0][ct], 0, 0, 0);
                acc[1][ct] = __builtin_amdgcn_mfma_f32_16x16x32_bf16(a1, bf, acc[1][ct], 0, 0, 0);
            }
        }
    }

    const int m   = n0 >> 10;                 // 0,1,2
    const int b   = row0 >> 11;
    const int tl0 = (row0 & (SEQ - 1)) + wave * 32;
    if (m < 2) {
        __hip_bfloat16* outp = qkv + ((m == 0) ? Q_OFF : K_OFF)
                             + (size_t)b * NH * SEQ * HD;
        #pragma unroll
        for (int rsub = 0; rsub < 2; ++rsub)
            #pragma unroll
            for (int ct = 0; ct < 8; ++ct) {
                const int h = (2 * nt + (ct >> 2)) & 15;
                const int d = (ct & 3) * 16 + lr;
                #pragma unroll
                for (int i = 0; i < 4; ++i) {
                    const int trow = tl0 + rsub * 16 + lg * 4 + i;
                    outp[((size_t)h * SEQ + trow) * HD + d] = __float2bfloat16(acc[rsub][ct][i]);
                }
            }
    } else {
        __hip_bfloat16 (*Ts)[136] = (__hip_bfloat16(*)[136])lds;
        __syncthreads();
        #pragma unroll
        for (int rsub = 0; rsub < 2; ++rsub)
            #pragma unroll
            for (int ct = 0; ct < 8; ++ct)
                #pragma unroll
                for (int i = 0; i < 4; ++i)
                    Ts[ct * 16 + lr][wave * 32 + rsub * 16 + lg * 4 + i] =
                        __float2bfloat16(acc[rsub][ct][i]);
        __syncthreads();
        const int c    = tid >> 1;
        const int tseg = (tid & 1) * 64;
        const int hv   = (2 * nt + (c >> 6)) & 15;
        const int dv   = c & 63;
        __hip_bfloat16* dst = qkv + V_OFF + ((size_t)b * NH + hv) * (HD * SEQ)
                            + (size_t)dv * SEQ + (row0 & (SEQ - 1)) + tseg;
        #pragma unroll
        for (int q = 0; q < 8; ++q)
            *(short8*)(dst + q * 8) = *(const short8*)&Ts[c][tseg + q * 8];
    }
}

// ---------------------------------------------------------------------------
// Kernel 2: causal flash attention, swapped-operand (S^T / O^T) structure.
// 512 blocks; each handles paired q-tiles (p, 15-p) -> uniform 34 kv-tiles.
// Lane owns one q-row: softmax in-lane + 2 shuffles; log2-domain, defer-max.
// ---------------------------------------------------------------------------
__global__ __launch_bounds__(256)
void attn_kernel(const __hip_bfloat16* __restrict__ ws, float* __restrict__ out)
{
    const int bid     = blockIdx.x;                 // 512
    const int logical = (bid & 7) * 64 + (bid >> 3);
    const int p  = logical & 7;
    const int h  = (logical >> 3) & 15;
    const int b  = logical >> 7;

    const __hip_bfloat16* qp = ws + Q_OFF + ((size_t)b * NH + h) * (SEQ * HD);
    const __hip_bfloat16* kp = ws + K_OFF + ((size_t)b * NH + h) * (SEQ * HD);
    const __hip_bfloat16* vt = ws + V_OFF + ((size_t)b * NH + h) * (HD * SEQ); // [d][t]

    __shared__ __hip_bfloat16 Ks[64][72];        // [key][d]
    __shared__ __hip_bfloat16 Vs[64][72];        // [d][key]
    __shared__ __hip_bfloat16 Ps[4][16][72];     // per-wave P [qrow][key]

    const int tid  = threadIdx.x;
    const int wave = tid >> 6;
    const int lane = tid & 63;
    const int lr   = lane & 15;
    const int lg   = lane >> 4;
    const int sr   = tid >> 2;
    const int sc   = (tid & 3) * 16;

    float* op = out + (size_t)b * SEQ * (NH * HD) + (size_t)h * HD;

    for (int seg = 0; seg < 2; ++seg) {
        const int qt    = seg ? (15 - p) : p;
        const int qbase = qt * 128;
        const int ktmax = 2 * qt + 1;

        // Q fragments (identical layout serves as MFMA B-operand)
        short8 qf[2][2];
        #pragma unroll
        for (int rsub = 0; rsub < 2; ++rsub) {
            const __hip_bfloat16* src =
                qp + (size_t)(qbase + wave * 32 + rsub * 16 + lr) * HD + lg * 8;
            qf[rsub][0] = *(const short8*)src;
            qf[rsub][1] = *(const short8*)(src + 32);
        }

        float m_run[2] = {-1e30f, -1e30f};
        float l_run[2] = {0.f, 0.f};
        f32x4 o_acc[2][4] = {};

        // prologue: stage kv-tile 0 (previous seg's post-PV barrier protects LDS)
        short8 kr0, kr1, vr0, vr1;
        kr0 = *(const short8*)(kp + (size_t)sr * HD + sc);
        kr1 = *(const short8*)(kp + (size_t)sr * HD + sc + 8);
        vr0 = *(const short8*)(vt + (size_t)sr * SEQ + sc);
        vr1 = *(const short8*)(vt + (size_t)sr * SEQ + sc + 8);
        *(short8*)&Ks[sr][sc]     = kr0;
        *(short8*)&Ks[sr][sc + 8] = kr1;
        *(short8*)&Vs[sr][sc]     = vr0;
        *(short8*)&Vs[sr][sc + 8] = vr1;
        __syncthreads();

        for (int kt = 0; kt <= ktmax; ++kt) {
            const int kbase = kt * 64;
            if (kt < ktmax) {   // T14: issue next-tile loads before compute
                const int nb = kbase + 64;
                kr0 = *(const short8*)(kp + (size_t)(nb + sr) * HD + sc);
                kr1 = *(const short8*)(kp + (size_t)(nb + sr) * HD + sc + 8);
                vr0 = *(const short8*)(vt + (size_t)sr * SEQ + nb + sc);
                vr1 = *(const short8*)(vt + (size_t)sr * SEQ + nb + sc + 8);
            }

            // S^T = K . Q^T : s[rsub][ct][i] = S[key=kbase+ct*16+lg*4+i][qrow(lr)]
            f32x4 s[2][4];
            #pragma unroll
            for (int ct = 0; ct < 4; ++ct) {
                short8 kf0 = *(const short8*)&Ks[ct * 16 + lr][lg * 8];
                short8 kf1 = *(const short8*)&Ks[ct * 16 + lr][32 + lg * 8];
                #pragma unroll
                for (int rsub = 0; rsub < 2; ++rsub) {
                    f32x4 z = {};
                    z           = __builtin_amdgcn_mfma_f32_16x16x32_bf16(kf0, qf[rsub][0], z, 0, 0, 0);
                    s[rsub][ct] = __builtin_amdgcn_mfma_f32_16x16x32_bf16(kf1, qf[rsub][1], z, 0, 0, 0);
                }
            }

            if (kt >= 2 * qt) {   // causal mask: key in regs, qrow in lane
                #pragma unroll
                for (int rsub = 0; rsub < 2; ++rsub) {
                    const int qrow = qbase + wave * 32 + rsub * 16 + lr;
                    #pragma unroll
                    for (int ct = 0; ct < 4; ++ct)
                        #pragma unroll
                        for (int i = 0; i < 4; ++i) {
                            const int key = kbase + ct * 16 + lg * 4 + i;
                            s[rsub][ct][i] = (key > qrow) ? -1e30f : s[rsub][ct][i];
                        }
                }
            }

            #pragma unroll
            for (int rsub = 0; rsub < 2; ++rsub) {
                // tile max: 15 in-lane + 2 cross-group shuffles
                float pmax = s[rsub][0][0];
                #pragma unroll
                for (int ct = 0; ct < 4; ++ct)
                    #pragma unroll
                    for (int i = 0; i < 4; ++i)
                        pmax = fmaxf(pmax, s[rsub][ct][i]);
                pmax = fmaxf(pmax, __shfl_xor(pmax, 16, 64));
                pmax = fmaxf(pmax, __shfl_xor(pmax, 32, 64));

                // T13 defer-max (log2 domain, THR=8 -> P <= 256)
                if (__any(pmax > m_run[rsub] + 8.0f)) {
                    const float mnew = fmaxf(m_run[rsub], pmax);
                    const float corr = __builtin_amdgcn_exp2f(m_run[rsub] - mnew);
                    l_run[rsub] *= corr;
                    #pragma unroll
                    for (int ct = 0; ct < 4; ++ct)
                        #pragma unroll
                        for (int i = 0; i < 4; ++i)
                            o_acc[rsub][ct][i] *= corr;
                    m_run[rsub] = mnew;
                }

                const float mcur = m_run[rsub];
                float rs0 = 0.f, rs1 = 0.f;
                #pragma unroll
                for (int ct = 0; ct < 4; ++ct) {
                    const float p0 = __builtin_amdgcn_exp2f(s[rsub][ct][0] - mcur);
                    const float p1 = __builtin_amdgcn_exp2f(s[rsub][ct][1] - mcur);
                    const float p2 = __builtin_amdgcn_exp2f(s[rsub][ct][2] - mcur);
                    const float p3 = __builtin_amdgcn_exp2f(s[rsub][ct][3] - mcur);
                    rs0 += p0 + p1;
                    rs1 += p2 + p3;
                    alignas(8) __hip_bfloat16 t[4] = {
                        __float2bfloat16(p0), __float2bfloat16(p1),
                        __float2bfloat16(p2), __float2bfloat16(p3)};
                    *(short4v*)&Ps[wave][lr][ct * 16 + lg * 4] = *(const short4v*)t;
                }
                float rs = rs0 + rs1;
                rs += __shfl_xor(rs, 16, 64);
                rs += __shfl_xor(rs, 32, 64);
                l_run[rsub] += rs;

                // P fragment (lane-local row) and O^T accumulate
                short8 pf0 = *(const short8*)&Ps[wave][lr][lg * 8];
                short8 pf1 = *(const short8*)&Ps[wave][lr][32 + lg * 8];
                #pragma unroll
                for (int ct = 0; ct < 4; ++ct) {
                    short8 vf0 = *(const short8*)&Vs[ct * 16 + lr][lg * 8];
                    short8 vf1 = *(const short8*)&Vs[ct * 16 + lr][32 + lg * 8];
                    o_acc[rsub][ct] = __builtin_amdgcn_mfma_f32_16x16x32_bf16(vf0, pf0, o_acc[rsub][ct], 0, 0, 0);
                    o_acc[rsub][ct] = __builtin_amdgcn_mfma_f32_16x16x32_bf16(vf1, pf1, o_acc[rsub][ct], 0, 0, 0);
                }
            }

            __syncthreads();                 // all waves done reading Ks/Vs
            if (kt < ktmax) {
                *(short8*)&Ks[sr][sc]     = kr0;
                *(short8*)&Ks[sr][sc + 8] = kr1;
                *(short8*)&Vs[sr][sc]     = vr0;
                *(short8*)&Vs[sr][sc + 8] = vr1;
                __syncthreads();
            }
        }

        // epilogue: O^T -> out[b][t][h*64+d]; qrow lane-local -> float4 stores
        #pragma unroll
        for (int rsub = 0; rsub < 2; ++rsub) {
            const float inv  = 1.0f / l_run[rsub];
            const int   trow = qbase + wave * 32 + rsub * 16 + lr;
            #pragma unroll
            for (int ct = 0; ct < 4; ++ct) {
                float4 o;
                o.x = o_acc[rsub][ct][0] * inv;
                o.y = o_acc[rsub][ct][1] * inv;
                o.z = o_acc[rsub][ct][2] * inv;
                o.w = o_acc[rsub][ct][3] * inv;
                *(float4*)&op[(size_t)trow * (NH * HD) + ct * 16 + lg * 4] = o;
            }
        }
    }
}

extern "C" void kernel_launch(void* const* d_in, const int* in_sizes, int n_in,
                              void* d_out, int out_size, void* d_ws, size_t ws_size,
                              hipStream_t stream) {
    const float* x  = (const float*)d_in[0];
    const float* Wq = (const float*)d_in[1];
    const float* Wk = (const float*)d_in[2];
    const float* Wv = (const float*)d_in[3];
    float* out = (float*)d_out;
    __hip_bfloat16* ws = (__hip_bfloat16*)d_ws;

    __hip_bfloat16* xb = (__hip_bfloat16*)d_out;   // overwritten by attn later

    hipLaunchKernelGGL(xcast_kernel, dim3((BATCH * SEQ * EMB) / (256 * 8)), dim3(256),
                       0, stream, x, xb);
    hipLaunchKernelGGL(wt_kernel, dim3(16, 48), dim3(256), 0, stream,
                       Wq, Wk, Wv, ws + WT_OFF);
    hipLaunchKernelGGL(qkv_proj_kernel, dim3(24, 64), dim3(256), 0, stream,
                       xb, ws + WT_OFF, ws);
    hipLaunchKernelGGL(attn_kernel, dim3(512), dim3(256), 0, stream, ws, out);
}

// Round 5
// 157.295 us; speedup vs baseline: 2.8228x; 1.0234x over previous
//
#include <hip/hip_runtime.h>
#include <hip/hip_bf16.h>

#define BATCH 4
#define SEQ   2048
#define EMB   1024
#define NH    16
#define HD    64

// workspace bf16-element offsets (total 28,311,552 elems = 56.6 MB)
#define Q_OFF  ((size_t)0)           // q  [B][H][T][D]  (0.125*log2e folded into Wq)
#define K_OFF  ((size_t)8388608)     // k  [B][H][T][D]
#define V_OFF  ((size_t)16777216)    // vT [B][H][D][T]
#define WT_OFF ((size_t)25165824)    // Wt [3072][1024] = [mh*64+d][e]

typedef __attribute__((ext_vector_type(8))) short short8;   // 8 bf16
typedef __attribute__((ext_vector_type(4))) short short4v;  // 4 bf16 (8B)
typedef __attribute__((ext_vector_type(4))) float f32x4;    // MFMA acc

__device__ __forceinline__ short8 pack8s(float4 a, float4 b, float s) {
    alignas(16) __hip_bfloat16 t[8] = {
        __float2bfloat16(a.x * s), __float2bfloat16(a.y * s),
        __float2bfloat16(a.z * s), __float2bfloat16(a.w * s),
        __float2bfloat16(b.x * s), __float2bfloat16(b.y * s),
        __float2bfloat16(b.z * s), __float2bfloat16(b.w * s)};
    return *reinterpret_cast<const short8*>(t);
}

// async global->LDS, 16B per lane. LDS dest is wave-uniform base + lane*16.
__device__ __forceinline__ void async16(void* lds, const void* g) {
    __builtin_amdgcn_global_load_lds(
        (const __attribute__((address_space(1))) unsigned int*)g,
        (__attribute__((address_space(3))) unsigned int*)lds, 16, 0, 0);
}

// ---------------------------------------------------------------------------
// Kernel A: x fp32 -> bf16 (linear). Output lives in d_out (overwritten later).
// ---------------------------------------------------------------------------
__global__ __launch_bounds__(256)
void xcast_kernel(const float* __restrict__ x, __hip_bfloat16* __restrict__ xb)
{
    const size_t i = ((size_t)blockIdx.x * 256 + threadIdx.x) * 8;
    float4 f0 = ((const float4*)(x + i))[0];
    float4 f1 = ((const float4*)(x + i))[1];
    *(short8*)(xb + i) = pack8s(f0, f1, 1.0f);
}

// ---------------------------------------------------------------------------
// Kernel B: W transpose+cast: W[h][e][d] fp32 -> Wt[mh*64+d][e] bf16.
// Wq rows scaled by 0.125*log2(e): attention softmax runs in log2 domain.
// ---------------------------------------------------------------------------
__global__ __launch_bounds__(256)
void wt_kernel(const float* __restrict__ Wq, const float* __restrict__ Wk,
               const float* __restrict__ Wv, __hip_bfloat16* __restrict__ Wt)
{
    const int et = blockIdx.x;               // 16 e-tiles of 64
    const int mh = blockIdx.y;               // 48
    const int m = mh >> 4, h = mh & 15;
    const float* W = ((m == 0) ? Wq : (m == 1) ? Wk : Wv) + (size_t)h * (EMB * HD);
    const float scale = (m == 0) ? 0.18033688011112042f : 1.0f;  // 0.125*log2(e)

    __shared__ __hip_bfloat16 T[64][72];     // [d][e-local]
    const int tid = threadIdx.x;
    const int r   = tid >> 2;                // 0..63
    const int seg = (tid & 3) * 16;

    {
        const float* src = W + (size_t)(et * 64 + r) * HD + seg;
        float4 f0 = ((const float4*)src)[0];
        float4 f1 = ((const float4*)src)[1];
        float4 f2 = ((const float4*)src)[2];
        float4 f3 = ((const float4*)src)[3];
        const float v[16] = {f0.x,f0.y,f0.z,f0.w, f1.x,f1.y,f1.z,f1.w,
                             f2.x,f2.y,f2.z,f2.w, f3.x,f3.y,f3.z,f3.w};
        #pragma unroll
        for (int j = 0; j < 16; ++j) T[seg + j][r] = __float2bfloat16(v[j] * scale);
    }
    __syncthreads();
    __hip_bfloat16* dst = Wt + ((size_t)mh * HD + r) * EMB + et * 64 + seg;
    *(short8*)dst       = *(const short8*)&T[r][seg];
    *(short8*)(dst + 8) = *(const short8*)&T[r][seg + 8];
}

// ---------------------------------------------------------------------------
// Kernel 1: QKV projection as bf16 GEMM (m97 structure) — unchanged.
// ---------------------------------------------------------------------------
__global__ __launch_bounds__(256)
void qkv_proj_kernel(const __hip_bfloat16* __restrict__ xb,   // [8192][1024]
                     const __hip_bfloat16* __restrict__ Wt,   // [3072][1024]
                     __hip_bfloat16* __restrict__ qkv)
{
    const int nt = blockIdx.x;               // 0..23 col tiles (2 heads each)
    const int rt = blockIdx.y;               // 0..63 row tiles
    const int row0 = rt * 128;
    const int n0   = nt * 128;

    __shared__ __hip_bfloat16 lds[17408];
    __hip_bfloat16* As = lds;                // [128][64] swizzled, row=128B
    __hip_bfloat16* Bs = lds + 8192;         // [128][64] swizzled

    const int tid  = threadIdx.x;
    const int wave = tid >> 6;
    const int lane = tid & 63;
    const int lr   = lane & 15;
    const int lg   = lane >> 4;

    const int srow  = lane >> 3;
    const int sslot = (lane & 7) ^ srow;
    const char* aSrc = (const char*)xb + (size_t)(row0 + wave * 32 + srow) * 2048 + sslot * 16;
    const char* bSrc = (const char*)Wt + (size_t)(n0   + wave * 32 + srow) * 2048 + sslot * 16;
    char* aDst = (char*)As + (size_t)(wave * 32) * 128;
    char* bDst = (char*)Bs + (size_t)(wave * 32) * 128;

    f32x4 acc[2][8] = {};

    for (int k0 = 0; k0 < EMB; k0 += 64) {
        __syncthreads();
        #pragma unroll
        for (int i = 0; i < 4; ++i) {
            async16(aDst + i * 1024, aSrc + (size_t)i * 16384 + k0 * 2);
            async16(bDst + i * 1024, bSrc + (size_t)i * 16384 + k0 * 2);
        }
        __syncthreads();

        #pragma unroll
        for (int half = 0; half < 2; ++half) {
            const int cg = half * 4 + lg;
            const int r0a = wave * 32 + lr;
            const int r1a = wave * 32 + 16 + lr;
            short8 a0 = *(const short8*)((char*)As + r0a * 128 + ((cg ^ (r0a & 7)) * 16));
            short8 a1 = *(const short8*)((char*)As + r1a * 128 + ((cg ^ (r1a & 7)) * 16));
            #pragma unroll
            for (int ct = 0; ct < 8; ++ct) {
                const int rb = ct * 16 + lr;
                short8 bf = *(const short8*)((char*)Bs + rb * 128 + ((cg ^ (rb & 7)) * 16));
                acc[0][ct] = __builtin_amdgcn_mfma_f32_16x16x32_bf16(a0, bf, acc[0][ct], 0, 0, 0);
                acc[1][ct] = __builtin_amdgcn_mfma_f32_16x16x32_bf16(a1, bf, acc[1][ct], 0, 0, 0);
            }
        }
    }

    const int m   = n0 >> 10;                 // 0,1,2
    const int b   = row0 >> 11;
    const int tl0 = (row0 & (SEQ - 1)) + wave * 32;
    if (m < 2) {
        __hip_bfloat16* outp = qkv + ((m == 0) ? Q_OFF : K_OFF)
                             + (size_t)b * NH * SEQ * HD;
        #pragma unroll
        for (int rsub = 0; rsub < 2; ++rsub)
            #pragma unroll
            for (int ct = 0; ct < 8; ++ct) {
                const int h = (2 * nt + (ct >> 2)) & 15;
                const int d = (ct & 3) * 16 + lr;
                #pragma unroll
                for (int i = 0; i < 4; ++i) {
                    const int trow = tl0 + rsub * 16 + lg * 4 + i;
                    outp[((size_t)h * SEQ + trow) * HD + d] = __float2bfloat16(acc[rsub][ct][i]);
                }
            }
    } else {
        __hip_bfloat16 (*Ts)[136] = (__hip_bfloat16(*)[136])lds;
        __syncthreads();
        #pragma unroll
        for (int rsub = 0; rsub < 2; ++rsub)
            #pragma unroll
            for (int ct = 0; ct < 8; ++ct)
                #pragma unroll
                for (int i = 0; i < 4; ++i)
                    Ts[ct * 16 + lr][wave * 32 + rsub * 16 + lg * 4 + i] =
                        __float2bfloat16(acc[rsub][ct][i]);
        __syncthreads();
        const int c    = tid >> 1;
        const int tseg = (tid & 1) * 64;
        const int hv   = (2 * nt + (c >> 6)) & 15;
        const int dv   = c & 63;
        __hip_bfloat16* dst = qkv + V_OFF + ((size_t)b * NH + hv) * (HD * SEQ)
                            + (size_t)dv * SEQ + (row0 & (SEQ - 1)) + tseg;
        #pragma unroll
        for (int q = 0; q < 8; ++q)
            *(short8*)(dst + q * 8) = *(const short8*)&Ts[c][tseg + q * 8];
    }
}

// ---------------------------------------------------------------------------
// Kernel 2: causal flash attention, swapped-operand (S^T / O^T).
// 512 paired blocks; XOR-swizzled dbuf K/V tiles staged via global_load_lds
// with source pre-swizzle; one barrier per kv-tile; swizzled Ps; setprio.
// ---------------------------------------------------------------------------
__global__ __launch_bounds__(256)
void attn_kernel(const __hip_bfloat16* __restrict__ ws, float* __restrict__ out)
{
    const int bid     = blockIdx.x;                 // 512
    const int logical = (bid & 7) * 64 + (bid >> 3);
    const int p  = logical & 7;
    const int h  = (logical >> 3) & 15;
    const int b  = logical >> 7;

    const __hip_bfloat16* qp = ws + Q_OFF + ((size_t)b * NH + h) * (SEQ * HD);
    const __hip_bfloat16* kp = ws + K_OFF + ((size_t)b * NH + h) * (SEQ * HD);
    const __hip_bfloat16* vt = ws + V_OFF + ((size_t)b * NH + h) * (HD * SEQ); // [d][t]

    // swizzled tiles: element slot s of row r at byte r*128 + ((s^(r&7))<<4)
    __shared__ __align__(16) __hip_bfloat16 Ksb[2][4096];   // [buf][64 key][64 d]
    __shared__ __align__(16) __hip_bfloat16 Vsb[2][4096];   // [buf][64 d][64 key]
    __shared__ __align__(16) __hip_bfloat16 Psb[4][1024];   // per-wave [16 q][64 key]

    const int tid  = threadIdx.x;
    const int wave = tid >> 6;
    const int lane = tid & 63;
    const int lr   = lane & 15;
    const int lg   = lane >> 4;
    const int l7   = lr & 7;

    const int srow8 = lane >> 3;            // 0..7 within an 8-row issue
    const int sslot = (lane & 7) ^ srow8;   // source pre-swizzle slot

    float* op = out + (size_t)b * SEQ * (NH * HD) + (size_t)h * HD;

    for (int seg = 0; seg < 2; ++seg) {
        const int qt    = seg ? (15 - p) : p;
        const int qbase = qt * 128;
        const int ktmax = 2 * qt + 1;

        // Q fragments (B-operand layout; scale folded in at projection)
        short8 qf[2][2];
        #pragma unroll
        for (int rsub = 0; rsub < 2; ++rsub) {
            const __hip_bfloat16* src =
                qp + (size_t)(qbase + wave * 32 + rsub * 16 + lr) * HD + lg * 8;
            qf[rsub][0] = *(const short8*)src;
            qf[rsub][1] = *(const short8*)(src + 32);
        }

        float m_run[2] = {-1e30f, -1e30f};
        float l_run[2] = {0.f, 0.f};
        f32x4 o_acc[2][4] = {};

        // async stage of one kv-tile into buf (each wave: 16 K rows + 16 V rows)
        auto stage = [&](int buf, int kbase) {
            #pragma unroll
            for (int j = 0; j < 2; ++j) {
                const int r0 = wave * 16 + j * 8;   // tile-local row base (mult of 8)
                async16((char*)Ksb[buf] + r0 * 128,
                        (const char*)(kp + (size_t)(kbase + r0 + srow8) * HD) + sslot * 16);
                async16((char*)Vsb[buf] + r0 * 128,
                        (const char*)(vt + (size_t)(r0 + srow8) * SEQ + kbase) + sslot * 16);
            }
        };

        stage(0, 0);
        __syncthreads();   // vmcnt(0) drain: tile 0 resident

        for (int kt = 0; kt <= ktmax; ++kt) {
            const int cur = kt & 1;
            if (kt < ktmax) stage(cur ^ 1, (kt + 1) * 64);   // T14: issue early

            // S^T = K . Q^T : s[rsub][ct][i] = S[key=ct*16+lg*4+i][qrow(lr)]
            f32x4 s[2][4];
            __builtin_amdgcn_s_setprio(1);
            #pragma unroll
            for (int ct = 0; ct < 4; ++ct) {
                const char* kb = (const char*)Ksb[cur] + (ct * 16 + lr) * 128;
                short8 kf0 = *(const short8*)(kb + ((lg      ^ l7) << 4));
                short8 kf1 = *(const short8*)(kb + (((lg + 4) ^ l7) << 4));
                #pragma unroll
                for (int rsub = 0; rsub < 2; ++rsub) {
                    f32x4 z = {};
                    z           = __builtin_amdgcn_mfma_f32_16x16x32_bf16(kf0, qf[rsub][0], z, 0, 0, 0);
                    s[rsub][ct] = __builtin_amdgcn_mfma_f32_16x16x32_bf16(kf1, qf[rsub][1], z, 0, 0, 0);
                }
            }
            __builtin_amdgcn_s_setprio(0);

            const int kbase = kt * 64;
            if (kt >= 2 * qt) {   // causal mask (diagonal tiles only)
                #pragma unroll
                for (int rsub = 0; rsub < 2; ++rsub) {
                    const int qrow = qbase + wave * 32 + rsub * 16 + lr;
                    #pragma unroll
                    for (int ct = 0; ct < 4; ++ct)
                        #pragma unroll
                        for (int i = 0; i < 4; ++i) {
                            const int key = kbase + ct * 16 + lg * 4 + i;
                            s[rsub][ct][i] = (key > qrow) ? -1e30f : s[rsub][ct][i];
                        }
                }
            }

            #pragma unroll
            for (int rsub = 0; rsub < 2; ++rsub) {
                // tile max: in-lane tree + 2 cross-group shuffles
                float pmax = fmaxf(
                    fmaxf(fmaxf(fmaxf(s[rsub][0][0], s[rsub][0][1]), fmaxf(s[rsub][0][2], s[rsub][0][3])),
                          fmaxf(fmaxf(s[rsub][1][0], s[rsub][1][1]), fmaxf(s[rsub][1][2], s[rsub][1][3]))),
                    fmaxf(fmaxf(fmaxf(s[rsub][2][0], s[rsub][2][1]), fmaxf(s[rsub][2][2], s[rsub][2][3])),
                          fmaxf(fmaxf(s[rsub][3][0], s[rsub][3][1]), fmaxf(s[rsub][3][2], s[rsub][3][3]))));
                pmax = fmaxf(pmax, __shfl_xor(pmax, 16, 64));
                pmax = fmaxf(pmax, __shfl_xor(pmax, 32, 64));

                // T13 defer-max (log2 domain, THR=8 -> P <= 256)
                if (__any(pmax > m_run[rsub] + 8.0f)) {
                    const float mnew = fmaxf(m_run[rsub], pmax);
                    const float corr = __builtin_amdgcn_exp2f(m_run[rsub] - mnew);
                    l_run[rsub] *= corr;
                    #pragma unroll
                    for (int ct = 0; ct < 4; ++ct)
                        #pragma unroll
                        for (int i = 0; i < 4; ++i)
                            o_acc[rsub][ct][i] *= corr;
                    m_run[rsub] = mnew;
                }

                const float mcur = m_run[rsub];
                float rs0 = 0.f, rs1 = 0.f;
                #pragma unroll
                for (int ct = 0; ct < 4; ++ct) {
                    const float p0 = __builtin_amdgcn_exp2f(s[rsub][ct][0] - mcur);
                    const float p1 = __builtin_amdgcn_exp2f(s[rsub][ct][1] - mcur);
                    const float p2 = __builtin_amdgcn_exp2f(s[rsub][ct][2] - mcur);
                    const float p3 = __builtin_amdgcn_exp2f(s[rsub][ct][3] - mcur);
                    rs0 += p0 + p1;
                    rs1 += p2 + p3;
                    alignas(8) __hip_bfloat16 t[4] = {
                        __float2bfloat16(p0), __float2bfloat16(p1),
                        __float2bfloat16(p2), __float2bfloat16(p3)};
                    // element 16ct+4lg -> slot 2ct+(lg>>1), sub-offset 8*(lg&1), row lr
                    *(short4v*)((char*)Psb[wave] + lr * 128
                        + (((2 * ct + (lg >> 1)) ^ l7) << 4) + 8 * (lg & 1)) = *(const short4v*)t;
                }
                float rs = rs0 + rs1;
                rs += __shfl_xor(rs, 16, 64);
                rs += __shfl_xor(rs, 32, 64);
                l_run[rsub] += rs;

                // P fragment (lane-local row) and O^T accumulate
                const char* pb = (const char*)Psb[wave] + lr * 128;
                short8 pf0 = *(const short8*)(pb + ((lg      ^ l7) << 4));
                short8 pf1 = *(const short8*)(pb + (((lg + 4) ^ l7) << 4));
                __builtin_amdgcn_s_setprio(1);
                #pragma unroll
                for (int ct = 0; ct < 4; ++ct) {
                    const char* vb = (const char*)Vsb[cur] + (ct * 16 + lr) * 128;
                    short8 vf0 = *(const short8*)(vb + ((lg      ^ l7) << 4));
                    short8 vf1 = *(const short8*)(vb + (((lg + 4) ^ l7) << 4));
                    o_acc[rsub][ct] = __builtin_amdgcn_mfma_f32_16x16x32_bf16(vf0, pf0, o_acc[rsub][ct], 0, 0, 0);
                    o_acc[rsub][ct] = __builtin_amdgcn_mfma_f32_16x16x32_bf16(vf1, pf1, o_acc[rsub][ct], 0, 0, 0);
                }
                __builtin_amdgcn_s_setprio(0);
            }

            __syncthreads();   // single barrier: drains async stage, fences dbuf swap
        }

        // epilogue: O^T -> out[b][t][h*64+d]; qrow lane-local -> float4 stores
        #pragma unroll
        for (int rsub = 0; rsub < 2; ++rsub) {
            const float inv  = 1.0f / l_run[rsub];
            const int   trow = qbase + wave * 32 + rsub * 16 + lr;
            #pragma unroll
            for (int ct = 0; ct < 4; ++ct) {
                float4 o;
                o.x = o_acc[rsub][ct][0] * inv;
                o.y = o_acc[rsub][ct][1] * inv;
                o.z = o_acc[rsub][ct][2] * inv;
                o.w = o_acc[rsub][ct][3] * inv;
                *(float4*)&op[(size_t)trow * (NH * HD) + ct * 16 + lg * 4] = o;
            }
        }
    }
}

extern "C" void kernel_launch(void* const* d_in, const int* in_sizes, int n_in,
                              void* d_out, int out_size, void* d_ws, size_t ws_size,
                              hipStream_t stream) {
    const float* x  = (const float*)d_in[0];
    const float* Wq = (const float*)d_in[1];
    const float* Wk = (const float*)d_in[2];
    const float* Wv = (const float*)d_in[3];
    float* out = (float*)d_out;
    __hip_bfloat16* ws = (__hip_bfloat16*)d_ws;

    __hip_bfloat16* xb = (__hip_bfloat16*)d_out;   // overwritten by attn later

    hipLaunchKernelGGL(xcast_kernel, dim3((BATCH * SEQ * EMB) / (256 * 8)), dim3(256),
                       0, stream, x, xb);
    hipLaunchKernelGGL(wt_kernel, dim3(16, 48), dim3(256), 0, stream,
                       Wq, Wk, Wv, ws + WT_OFF);
    hipLaunchKernelGGL(qkv_proj_kernel, dim3(24, 64), dim3(256), 0, stream,
                       xb, ws + WT_OFF, ws);
    hipLaunchKernelGGL(attn_kernel, dim3(512), dim3(256), 0, stream, ws, out);
}